// Round 3
// baseline (1352.321 us; speedup 1.0000x reference)
//
#include <hip/hip_runtime.h>

// SparseFormer forward, MI355X gfx950.
// Round 3: inputs fp32 (confirmed: bf16-misread gave NaN in R1), OUTPUT fp32
// (R2's 0.3847 error == same-scale shuffle from reading packed bf16 as fp32).
// Chaotic path (offsets->pts) computed fully in fp32; heavy intermediates bf16.
//   kdetect : ln_w bit pattern -> flag (0=fp32 inputs, 1=bf16) [insurance]
//   k0: img (B,C,H,W) -> featT (B,H*W,C) bf16   [tier A]
//   k1: offsets GEMV + point norm (unbiased std) -> pts(fp32) ; LN@W1+b1 -> hidden(fp32)
//   k2: bilinear gather -> sampled[4096][64][64] bf16
//   k4: params = hidden @ W2 + b2 -> bf16
//   k5: x1=gelu(sampled@cm+m_beta); x2=gelu(sm@x1+s_beta) (overwrite sampled)
//   k6: out = x2flat @ W_out + b_out -> d_out fp32
// B=64 N=64 DIM=256 HEADS=4 P=16 H=W=56 CH=64; tokens=4096.

typedef unsigned short u16;
typedef u16 u16x8 __attribute__((ext_vector_type(8)));

static __device__ __forceinline__ float bf2f(u16 s) {
    union { float f; unsigned u; } v; v.u = ((unsigned)s) << 16; return v.f;
}
static __device__ __forceinline__ u16 f2bf(float f) {
    union { float f; unsigned u; } v; v.f = f;
    unsigned r = v.u + 0x7fffu + ((v.u >> 16) & 1u);   // RNE
    return (u16)(r >> 16);
}
static __device__ __forceinline__ float gelu(float x) {
    return 0.5f * x * (1.0f + erff(x * 0.70710678118654752f));
}
static __device__ __forceinline__ float loadf(const void* p, size_t i, int isbf) {
    return isbf ? bf2f(((const u16*)p)[i]) : ((const float*)p)[i];
}

// ---------------- dtype detect --------------------------------------------
__global__ void kdetect(const void* __restrict__ lnw, int* __restrict__ flag) {
    if (threadIdx.x == 0) {
        unsigned v = *(const unsigned*)lnw;
        *flag = (v == 0x3F800000u) ? 0 : 1;   // fp32 1.0 vs packed bf16 ones
    }
}

// ---------------- k0: transpose (B,256,3136) -> (B,3136,256) bf16 ----------
__global__ void k0_transpose(const void* __restrict__ img, u16* __restrict__ featT,
                             const int* __restrict__ flag) {
    __shared__ __align__(16) float tile[64 * 65];
    const int pos0 = blockIdx.x * 64, c0 = blockIdx.y * 64, bz = blockIdx.z;
    const int tid = threadIdx.x;
    const int isbf = *flag;
#pragma unroll
    for (int i = 0; i < 16; i++) {
        int e = i * 256 + tid;
        int cy = e >> 6, px = e & 63;
        tile[cy * 65 + px] = loadf(img, ((size_t)bz * 256 + c0 + cy) * 3136 + pos0 + px, isbf);
    }
    __syncthreads();
#pragma unroll
    for (int i = 0; i < 16; i++) {
        int e = i * 256 + tid;
        int cy = e & 63, px = e >> 6;
        featT[((size_t)bz * 3136 + pos0 + px) * 256 + c0 + cy] = f2bf(tile[cy * 65 + px]);
    }
}

// ---------------- k1: offsets -> pts ; LN -> hidden (all fp32) -------------
__global__ void k1_points(const void* __restrict__ query, const void* __restrict__ roi,
                          const void* __restrict__ W_off, const void* __restrict__ b_off,
                          const void* __restrict__ ln_w, const void* __restrict__ ln_b,
                          const void* __restrict__ W1, const void* __restrict__ b1,
                          const int* __restrict__ flag,
                          float* __restrict__ pts, float* __restrict__ hbuf) {
    __shared__ float qf[256], qn[256], offl[128], red[4], stats[8];
    const int t = blockIdx.x, tid = threadIdx.x;
    const int isbf = *flag;
    float q = loadf(query, (size_t)t * 256 + tid, isbf);
    qf[tid] = q;
    float v = q;
#pragma unroll
    for (int o = 32; o; o >>= 1) v += __shfl_down(v, o, 64);
    if ((tid & 63) == 0) red[tid >> 6] = v;
    __syncthreads();
    if (tid == 0) stats[0] = (red[0] + red[1] + red[2] + red[3]) * (1.f / 256.f);
    __syncthreads();
    float mu = stats[0];
    float dv = q - mu;
    v = dv * dv;
#pragma unroll
    for (int o = 32; o; o >>= 1) v += __shfl_down(v, o, 64);
    if ((tid & 63) == 0) red[tid >> 6] = v;
    __syncthreads();
    if (tid == 0) stats[1] = (red[0] + red[1] + red[2] + red[3]) * (1.f / 256.f);
    __syncthreads();
    float inv = rsqrtf(stats[1] + 1e-6f);
    qn[tid] = dv * inv * loadf(ln_w, tid, isbf) + loadf(ln_b, tid, isbf);
    __syncthreads();
    if (tid < 128) {                        // offsets use RAW query (fp32 exact)
        float a = loadf(b_off, tid, isbf);
        for (int d = 0; d < 256; d++) a = fmaf(qf[d], loadf(W_off, (size_t)d * 128 + tid, isbf), a);
        offl[tid] = a;
    } else if (tid < 192) {                 // hidden uses LN'd query
        int k = tid - 128;
        float a = loadf(b1, k, isbf);
        for (int d = 0; d < 256; d++) a = fmaf(qn[d], loadf(W1, (size_t)d * 64 + k, isbf), a);
        hbuf[(size_t)t * 64 + k] = a;
    }
    __syncthreads();
    if (tid < 2) {                          // per-coord mean / unbiased std over 64 pts
        float m = 0.f;
        for (int p = 0; p < 64; p++) m += offl[p * 2 + tid];
        m *= (1.f / 64.f);
        float s2 = 0.f;
        for (int p = 0; p < 64; p++) { float d = offl[p * 2 + tid] - m; s2 += d * d; }
        float sd = sqrtf(s2 * (1.f / 63.f));
        stats[2 + tid] = m;
        stats[4 + tid] = 1.f / (3.f * (sd + 1e-7f));
    }
    __syncthreads();
    if (tid < 128) {
        int xy = tid & 1;
        float lo = loadf(roi, (size_t)t * 4 + xy, isbf);
        float hi = loadf(roi, (size_t)t * 4 + 2 + xy, isbf);
        float ctr = 0.5f * (lo + hi), wh = hi - lo;
        pts[(size_t)t * 128 + tid] = ctr + (offl[tid] - stats[2 + xy]) * stats[4 + xy] * wh;
    }
}

// ---------------- k2: bilinear gather --------------------------------------
__global__ void k2_sample_t(const u16* __restrict__ featT, const float* __restrict__ pts,
                            u16* __restrict__ sampled) {
    const int t = blockIdx.x, tid = threadIdx.x;
    const int pt = tid >> 2, cg = tid & 3;
    const int b = t >> 6, hh = pt >> 4;
    const float px = pts[(size_t)t * 128 + pt * 2], py = pts[(size_t)t * 128 + pt * 2 + 1];
    const float x = px * 56.f - 0.5f, y = py * 56.f - 0.5f;
    const float x0f = floorf(x), y0f = floorf(y);
    const int ix0 = (int)x0f, iy0 = (int)y0f;
    const float wx1 = x - x0f, wx0 = 1.f - wx1, wy1 = y - y0f, wy0 = 1.f - wy1;
    float acc[16];
#pragma unroll
    for (int i = 0; i < 16; i++) acc[i] = 0.f;
    const int chbase = hh * 64 + cg * 16;
#pragma unroll
    for (int corner = 0; corner < 4; corner++) {
        const int xi = ix0 + (corner & 1), yi = iy0 + (corner >> 1);
        const float wgt = ((corner & 1) ? wx1 : wx0) * ((corner >> 1) ? wy1 : wy0);
        if (xi >= 0 && xi < 56 && yi >= 0 && yi < 56) {
            const u16x8* p8 = (const u16x8*)&featT[((size_t)b * 3136 + yi * 56 + xi) * 256 + chbase];
            u16x8 a = p8[0], c = p8[1];
#pragma unroll
            for (int i = 0; i < 8; i++) {
                acc[i]     = fmaf(wgt, bf2f(a[i]), acc[i]);
                acc[8 + i] = fmaf(wgt, bf2f(c[i]), acc[8 + i]);
            }
        }
    }
    u16x8 o0, o1;
#pragma unroll
    for (int i = 0; i < 8; i++) { o0[i] = f2bf(acc[i]); o1[i] = f2bf(acc[8 + i]); }
    u16x8* q8 = (u16x8*)&sampled[(size_t)t * 4096 + pt * 64 + cg * 16];
    q8[0] = o0; q8[1] = o1;
}

__global__ void k2_sample_d(const void* __restrict__ img, const float* __restrict__ pts,
                            u16* __restrict__ sampled, const int* __restrict__ flag) {
    const int t = blockIdx.x, tid = threadIdx.x;
    const int pt = tid >> 2, cg = tid & 3;
    const int b = t >> 6, hh = pt >> 4;
    const int isbf = *flag;
    const float px = pts[(size_t)t * 128 + pt * 2], py = pts[(size_t)t * 128 + pt * 2 + 1];
    const float x = px * 56.f - 0.5f, y = py * 56.f - 0.5f;
    const float x0f = floorf(x), y0f = floorf(y);
    const int ix0 = (int)x0f, iy0 = (int)y0f;
    const float wx1 = x - x0f, wx0 = 1.f - wx1, wy1 = y - y0f, wy0 = 1.f - wy1;
    float acc[16];
#pragma unroll
    for (int i = 0; i < 16; i++) acc[i] = 0.f;
    const int chbase = b * 256 + hh * 64 + cg * 16;
#pragma unroll
    for (int corner = 0; corner < 4; corner++) {
        const int xi = ix0 + (corner & 1), yi = iy0 + (corner >> 1);
        const float wgt = ((corner & 1) ? wx1 : wx0) * ((corner >> 1) ? wy1 : wy0);
        if (xi >= 0 && xi < 56 && yi >= 0 && yi < 56) {
            const size_t sp = yi * 56 + xi;
#pragma unroll
            for (int i = 0; i < 16; i++)
                acc[i] = fmaf(wgt, loadf(img, ((size_t)(chbase + i)) * 3136 + sp, isbf), acc[i]);
        }
    }
    for (int i = 0; i < 16; i++)
        sampled[(size_t)t * 4096 + pt * 64 + cg * 16 + i] = f2bf(acc[i]);
}

// ---------------- k4: params = hidden @ W2 + b2 ----------------------------
__global__ void k4_params(const float* __restrict__ hbuf, const void* __restrict__ W2,
                          const void* __restrict__ b2, const int* __restrict__ flag,
                          u16* __restrict__ params) {
    __shared__ __align__(16) float hl[64 * 64];   // [token][k]
    const int tid = threadIdx.x;
    const int col = blockIdx.x * 256 + tid;
    const int tok0 = blockIdx.y * 64;
    const int isbf = *flag;
#pragma unroll
    for (int i = 0; i < 16; i++) {
        int e = i * 256 + tid;
        hl[e] = hbuf[(size_t)tok0 * 64 + e];
    }
    __syncthreads();
    float acc[64];
#pragma unroll
    for (int t = 0; t < 64; t++) acc[t] = 0.f;
    for (int k = 0; k < 64; k += 4) {
        const float w0 = loadf(W2, (size_t)(k + 0) * 8192 + col, isbf);
        const float w1 = loadf(W2, (size_t)(k + 1) * 8192 + col, isbf);
        const float w2 = loadf(W2, (size_t)(k + 2) * 8192 + col, isbf);
        const float w3 = loadf(W2, (size_t)(k + 3) * 8192 + col, isbf);
#pragma unroll
        for (int t = 0; t < 64; t++) {
            float4 h4 = *(const float4*)&hl[t * 64 + k];
            acc[t] = fmaf(h4.x, w0, acc[t]);
            acc[t] = fmaf(h4.y, w1, acc[t]);
            acc[t] = fmaf(h4.z, w2, acc[t]);
            acc[t] = fmaf(h4.w, w3, acc[t]);
        }
    }
    const float bb = loadf(b2, col, isbf);
#pragma unroll
    for (int t = 0; t < 64; t++)
        params[(size_t)(tok0 + t) * 8192 + col] = f2bf(acc[t] + bb);
}

// ---------------- k5: adaptive mixing per token ----------------------------
__global__ void k5_mix(const u16* __restrict__ params, const void* __restrict__ m_beta,
                       const void* __restrict__ s_beta, const int* __restrict__ flag,
                       u16* __restrict__ sampled) {
    __shared__ __align__(16) float s[4096];   // sampled [p][c]
    __shared__ __align__(16) float cw[4096];  // cm then sm
    __shared__ __align__(16) float x1[4096];  // [p][d]
    const int t = blockIdx.x, tid = threadIdx.x;
    const int isbf = *flag;
    const size_t pbase = (size_t)t * 8192, sbase = (size_t)t * 4096;
#pragma unroll
    for (int i = 0; i < 16; i++) {
        int e = i * 256 + tid;
        s[e]  = bf2f(sampled[sbase + e]);
        cw[e] = bf2f(params[pbase + e]);    // cm[c][d]
    }
    __syncthreads();
    float r[16];
#pragma unroll
    for (int i = 0; i < 16; i++) {
        int e = i * 256 + tid;
        int p = e >> 6, d = e & 63;
        float a = loadf(m_beta, d, isbf);
        for (int c = 0; c < 64; c += 4) {
            float4 sv = *(const float4*)&s[p * 64 + c];
            a = fmaf(sv.x, cw[(c + 0) * 64 + d], a);
            a = fmaf(sv.y, cw[(c + 1) * 64 + d], a);
            a = fmaf(sv.z, cw[(c + 2) * 64 + d], a);
            a = fmaf(sv.w, cw[(c + 3) * 64 + d], a);
        }
        r[i] = gelu(a);
    }
    __syncthreads();
#pragma unroll
    for (int i = 0; i < 16; i++) {
        int e = i * 256 + tid;
        x1[e] = r[i];
        cw[e] = bf2f(params[pbase + 4096 + e]);   // sm[o][p]
    }
    __syncthreads();
#pragma unroll
    for (int i = 0; i < 16; i++) {
        int e = i * 256 + tid;
        int o = e >> 6, c = e & 63;
        float a = loadf(s_beta, o, isbf);
        for (int p = 0; p < 64; p += 4) {
            float4 mv = *(const float4*)&cw[o * 64 + p];
            a = fmaf(mv.x, x1[(p + 0) * 64 + c], a);
            a = fmaf(mv.y, x1[(p + 1) * 64 + c], a);
            a = fmaf(mv.z, x1[(p + 2) * 64 + c], a);
            a = fmaf(mv.w, x1[(p + 3) * 64 + c], a);
        }
        sampled[sbase + e] = f2bf(gelu(a));       // overwrite with x2
    }
}

// ---------------- k6: out = x2flat @ W_out + b_out -> fp32 -----------------
__global__ void k6_out(const u16* __restrict__ x2b, const void* __restrict__ W_out,
                       const void* __restrict__ b_out, const int* __restrict__ flag,
                       float* __restrict__ out) {
    __shared__ __align__(16) float xt[8 * 128];
    const int t0 = blockIdx.x * 8, tid = threadIdx.x;
    const int isbf = *flag;
    float acc[8];
#pragma unroll
    for (int i = 0; i < 8; i++) acc[i] = 0.f;
    for (int kt = 0; kt < 32; kt++) {
#pragma unroll
        for (int i = 0; i < 4; i++) {
            int e = i * 256 + tid;
            int tt = e >> 7, kk = e & 127;
            xt[e] = bf2f(x2b[(size_t)(t0 + tt) * 4096 + kt * 128 + kk]);
        }
        __syncthreads();
        for (int kk = 0; kk < 128; kk += 4) {
            const int kg = kt * 128 + kk;
            const float w0 = loadf(W_out, (size_t)(kg + 0) * 256 + tid, isbf);
            const float w1 = loadf(W_out, (size_t)(kg + 1) * 256 + tid, isbf);
            const float w2 = loadf(W_out, (size_t)(kg + 2) * 256 + tid, isbf);
            const float w3 = loadf(W_out, (size_t)(kg + 3) * 256 + tid, isbf);
#pragma unroll
            for (int tt = 0; tt < 8; tt++) {
                float4 xv = *(const float4*)&xt[tt * 128 + kk];
                acc[tt] = fmaf(xv.x, w0, acc[tt]);
                acc[tt] = fmaf(xv.y, w1, acc[tt]);
                acc[tt] = fmaf(xv.z, w2, acc[tt]);
                acc[tt] = fmaf(xv.w, w3, acc[tt]);
            }
        }
        __syncthreads();
    }
    const float bo = loadf(b_out, tid, isbf);
#pragma unroll
    for (int tt = 0; tt < 8; tt++)
        out[(size_t)(t0 + tt) * 256 + tid] = acc[tt] + bo;
}

extern "C" void kernel_launch(void* const* d_in, const int* in_sizes, int n_in,
                              void* d_out, int out_size, void* d_ws, size_t ws_size,
                              hipStream_t stream) {
    const void* img    = d_in[0];
    const void* roi    = d_in[1];
    const void* query  = d_in[2];
    const void* W_off  = d_in[3];
    const void* b_off  = d_in[4];
    const void* ln_w   = d_in[5];
    const void* ln_b   = d_in[6];
    const void* W1     = d_in[7];
    const void* b1     = d_in[8];
    const void* W2     = d_in[9];
    const void* b2     = d_in[10];
    const void* m_beta = d_in[11];
    const void* s_beta = d_in[12];
    const void* W_out  = d_in[13];
    const void* b_out  = d_in[14];

    char* ws = (char*)d_ws;
    // ws layout (bytes):
    //   flag    @ 0
    //   pts     @ 1,024       : 4096*128*4  = 2,097,152 (fp32)   -> 2,098,176
    //   hidden  @ 2,098,176   : 4096*64*4   = 1,048,576 (fp32)   -> 3,146,752
    //   sampled @ 3,146,752   : 4096*4096*2 = 33,554,432 (bf16)  -> 36,701,184
    //   params  @ 36,701,184  : 4096*8192*2 = 67,108,864 (bf16)  -> 103,810,048
    //   featT   @ 103,810,048 : 64*3136*256*2 = 102,760,448 (bf16, tier A) -> 206,570,496
    int*   flag    = (int*)(ws + 0);
    float* pts     = (float*)(ws + 1024);
    float* hbuf    = (float*)(ws + 2098176);
    u16*   sampled = (u16*)(ws + 3146752);
    u16*   params  = (u16*)(ws + 36701184);
    u16*   featT   = (u16*)(ws + 103810048);
    const bool tierA = ws_size >= (size_t)206570496;

    kdetect<<<1, 64, 0, stream>>>(ln_w, flag);
    k1_points<<<4096, 256, 0, stream>>>(query, roi, W_off, b_off, ln_w, ln_b, W1, b1,
                                        flag, pts, hbuf);
    if (tierA) {
        k0_transpose<<<dim3(49, 4, 64), 256, 0, stream>>>(img, featT, flag);
        k2_sample_t<<<4096, 256, 0, stream>>>(featT, pts, sampled);
    } else {
        k2_sample_d<<<4096, 256, 0, stream>>>(img, pts, sampled, flag);
    }
    k4_params<<<dim3(32, 64), 256, 0, stream>>>(hbuf, W2, b2, flag, params);
    k5_mix<<<4096, 256, 0, stream>>>(params, m_beta, s_beta, flag, sampled);
    k6_out<<<512, 256, 0, stream>>>(sampled, W_out, b_out, flag, (float*)d_out);
}

// Round 4
// 588.944 us; speedup vs baseline: 2.2962x; 2.2962x over previous
//
#include <hip/hip_runtime.h>

// SparseFormer forward, MI355X gfx950. Round 4: MFMA-ize k4/k5/k6.
// Inputs fp32 (runtime-flag fallback to bf16 kept), output fp32.
//   kdetect : dtype flag
//   k0: img (B,C,H,W) -> featT (B,H*W,C) bf16   [tier A]
//   k1: offsets GEMV + point norm -> pts(fp32) ; LN@W1+b1 -> hidden(bf16)
//   k2: bilinear gather -> sampled[4096][64][64] bf16
//   k4: MFMA params = hidden[4096x64] @ W2[64x8192] + b2 -> bf16
//   k5: MFMA per-token: x1=gelu(s@cm+mb); x2=gelu(sm@x1+sb) -> sampled
//   k6: MFMA out = x2[4096x4096] @ W_out[4096x256] + b_out -> fp32
// MFMA 16x16x32 bf16 layouts (HW-verified, learn_hip m89/m91/m120):
//   A: lane m=lane&15, k=quad*8+j ; B: lane n=lane&15, k=quad*8+j (from LDS B^T)
//   C/D: col=lane&15, row=quad*4+reg
// LDS tiles stride 72 bf16 (pad) -> balanced banks on ds_read_b128 fragments.

typedef unsigned short u16;
typedef u16 u16x8 __attribute__((ext_vector_type(8)));
typedef short bf16x8 __attribute__((ext_vector_type(8)));
typedef float f32x4 __attribute__((ext_vector_type(4)));
#define SA 72
#define MFMA(a, b, c) __builtin_amdgcn_mfma_f32_16x16x32_bf16(a, b, c, 0, 0, 0)

static __device__ __forceinline__ float bf2f(u16 s) {
    union { float f; unsigned u; } v; v.u = ((unsigned)s) << 16; return v.f;
}
static __device__ __forceinline__ u16 f2bf(float f) {
    union { float f; unsigned u; } v; v.f = f;
    unsigned r = v.u + 0x7fffu + ((v.u >> 16) & 1u);   // RNE
    return (u16)(r >> 16);
}
static __device__ __forceinline__ float gelu(float x) {
    return 0.5f * x * (1.0f + erff(x * 0.70710678118654752f));
}
static __device__ __forceinline__ float loadf(const void* p, size_t i, int isbf) {
    return isbf ? bf2f(((const u16*)p)[i]) : ((const float*)p)[i];
}

// ---------------- dtype detect --------------------------------------------
__global__ void kdetect(const void* __restrict__ lnw, int* __restrict__ flag) {
    if (threadIdx.x == 0) {
        unsigned v = *(const unsigned*)lnw;
        *flag = (v == 0x3F800000u) ? 0 : 1;
    }
}

// ---------------- k0: transpose (B,256,3136) -> (B,3136,256) bf16 ----------
__global__ void k0_transpose(const void* __restrict__ img, u16* __restrict__ featT,
                             const int* __restrict__ flag) {
    __shared__ __align__(16) float tile[64 * 65];
    const int pos0 = blockIdx.x * 64, c0 = blockIdx.y * 64, bz = blockIdx.z;
    const int tid = threadIdx.x;
    const int isbf = *flag;
#pragma unroll
    for (int i = 0; i < 16; i++) {
        int e = i * 256 + tid;
        int cy = e >> 6, px = e & 63;
        tile[cy * 65 + px] = loadf(img, ((size_t)bz * 256 + c0 + cy) * 3136 + pos0 + px, isbf);
    }
    __syncthreads();
#pragma unroll
    for (int i = 0; i < 16; i++) {
        int e = i * 256 + tid;
        int cy = e & 63, px = e >> 6;
        featT[((size_t)bz * 3136 + pos0 + px) * 256 + c0 + cy] = f2bf(tile[cy * 65 + px]);
    }
}

// ---------------- k1: offsets -> pts ; LN -> hidden(bf16) ------------------
__global__ void k1_points(const void* __restrict__ query, const void* __restrict__ roi,
                          const void* __restrict__ W_off, const void* __restrict__ b_off,
                          const void* __restrict__ ln_w, const void* __restrict__ ln_b,
                          const void* __restrict__ W1, const void* __restrict__ b1,
                          const int* __restrict__ flag,
                          float* __restrict__ pts, u16* __restrict__ hbuf) {
    __shared__ float qf[256], qn[256], offl[128], red[4], stats[8];
    const int t = blockIdx.x, tid = threadIdx.x;
    const int isbf = *flag;
    float q = loadf(query, (size_t)t * 256 + tid, isbf);
    qf[tid] = q;
    float v = q;
#pragma unroll
    for (int o = 32; o; o >>= 1) v += __shfl_down(v, o, 64);
    if ((tid & 63) == 0) red[tid >> 6] = v;
    __syncthreads();
    if (tid == 0) stats[0] = (red[0] + red[1] + red[2] + red[3]) * (1.f / 256.f);
    __syncthreads();
    float mu = stats[0];
    float dv = q - mu;
    v = dv * dv;
#pragma unroll
    for (int o = 32; o; o >>= 1) v += __shfl_down(v, o, 64);
    if ((tid & 63) == 0) red[tid >> 6] = v;
    __syncthreads();
    if (tid == 0) stats[1] = (red[0] + red[1] + red[2] + red[3]) * (1.f / 256.f);
    __syncthreads();
    float inv = rsqrtf(stats[1] + 1e-6f);
    qn[tid] = dv * inv * loadf(ln_w, tid, isbf) + loadf(ln_b, tid, isbf);
    __syncthreads();
    if (tid < 128) {                        // offsets use RAW query
        float a = loadf(b_off, tid, isbf);
        for (int d = 0; d < 256; d++) a = fmaf(qf[d], loadf(W_off, (size_t)d * 128 + tid, isbf), a);
        offl[tid] = a;
    } else if (tid < 192) {                 // hidden uses LN'd query
        int k = tid - 128;
        float a = loadf(b1, k, isbf);
        for (int d = 0; d < 256; d++) a = fmaf(qn[d], loadf(W1, (size_t)d * 64 + k, isbf), a);
        hbuf[(size_t)t * 64 + k] = f2bf(a);
    }
    __syncthreads();
    if (tid < 2) {
        float m = 0.f;
        for (int p = 0; p < 64; p++) m += offl[p * 2 + tid];
        m *= (1.f / 64.f);
        float s2 = 0.f;
        for (int p = 0; p < 64; p++) { float d = offl[p * 2 + tid] - m; s2 += d * d; }
        float sd = sqrtf(s2 * (1.f / 63.f));
        stats[2 + tid] = m;
        stats[4 + tid] = 1.f / (3.f * (sd + 1e-7f));
    }
    __syncthreads();
    if (tid < 128) {
        int xy = tid & 1;
        float lo = loadf(roi, (size_t)t * 4 + xy, isbf);
        float hi = loadf(roi, (size_t)t * 4 + 2 + xy, isbf);
        float ctr = 0.5f * (lo + hi), wh = hi - lo;
        pts[(size_t)t * 128 + tid] = ctr + (offl[tid] - stats[2 + xy]) * stats[4 + xy] * wh;
    }
}

// ---------------- k2: bilinear gather --------------------------------------
__global__ void k2_sample_t(const u16* __restrict__ featT, const float* __restrict__ pts,
                            u16* __restrict__ sampled) {
    const int t = blockIdx.x, tid = threadIdx.x;
    const int pt = tid >> 2, cg = tid & 3;
    const int b = t >> 6, hh = pt >> 4;
    const float px = pts[(size_t)t * 128 + pt * 2], py = pts[(size_t)t * 128 + pt * 2 + 1];
    const float x = px * 56.f - 0.5f, y = py * 56.f - 0.5f;
    const float x0f = floorf(x), y0f = floorf(y);
    const int ix0 = (int)x0f, iy0 = (int)y0f;
    const float wx1 = x - x0f, wx0 = 1.f - wx1, wy1 = y - y0f, wy0 = 1.f - wy1;
    float acc[16];
#pragma unroll
    for (int i = 0; i < 16; i++) acc[i] = 0.f;
    const int chbase = hh * 64 + cg * 16;
#pragma unroll
    for (int corner = 0; corner < 4; corner++) {
        const int xi = ix0 + (corner & 1), yi = iy0 + (corner >> 1);
        const float wgt = ((corner & 1) ? wx1 : wx0) * ((corner >> 1) ? wy1 : wy0);
        if (xi >= 0 && xi < 56 && yi >= 0 && yi < 56) {
            const u16x8* p8 = (const u16x8*)&featT[((size_t)b * 3136 + yi * 56 + xi) * 256 + chbase];
            u16x8 a = p8[0], c = p8[1];
#pragma unroll
            for (int i = 0; i < 8; i++) {
                acc[i]     = fmaf(wgt, bf2f(a[i]), acc[i]);
                acc[8 + i] = fmaf(wgt, bf2f(c[i]), acc[8 + i]);
            }
        }
    }
    u16x8 o0, o1;
#pragma unroll
    for (int i = 0; i < 8; i++) { o0[i] = f2bf(acc[i]); o1[i] = f2bf(acc[8 + i]); }
    u16x8* q8 = (u16x8*)&sampled[(size_t)t * 4096 + pt * 64 + cg * 16];
    q8[0] = o0; q8[1] = o1;
}

__global__ void k2_sample_d(const void* __restrict__ img, const float* __restrict__ pts,
                            u16* __restrict__ sampled, const int* __restrict__ flag) {
    const int t = blockIdx.x, tid = threadIdx.x;
    const int pt = tid >> 2, cg = tid & 3;
    const int b = t >> 6, hh = pt >> 4;
    const int isbf = *flag;
    const float px = pts[(size_t)t * 128 + pt * 2], py = pts[(size_t)t * 128 + pt * 2 + 1];
    const float x = px * 56.f - 0.5f, y = py * 56.f - 0.5f;
    const float x0f = floorf(x), y0f = floorf(y);
    const int ix0 = (int)x0f, iy0 = (int)y0f;
    const float wx1 = x - x0f, wx0 = 1.f - wx1, wy1 = y - y0f, wy0 = 1.f - wy1;
    float acc[16];
#pragma unroll
    for (int i = 0; i < 16; i++) acc[i] = 0.f;
    const int chbase = b * 256 + hh * 64 + cg * 16;
#pragma unroll
    for (int corner = 0; corner < 4; corner++) {
        const int xi = ix0 + (corner & 1), yi = iy0 + (corner >> 1);
        const float wgt = ((corner & 1) ? wx1 : wx0) * ((corner >> 1) ? wy1 : wy0);
        if (xi >= 0 && xi < 56 && yi >= 0 && yi < 56) {
            const size_t sp = yi * 56 + xi;
#pragma unroll
            for (int i = 0; i < 16; i++)
                acc[i] = fmaf(wgt, loadf(img, ((size_t)(chbase + i)) * 3136 + sp, isbf), acc[i]);
        }
    }
    for (int i = 0; i < 16; i++)
        sampled[(size_t)t * 4096 + pt * 64 + cg * 16 + i] = f2bf(acc[i]);
}

// ---------------- k4: MFMA params = hidden @ W2 + b2 -----------------------
// grid (64 m, 128 n), block 256 = 4 waves; 64x64 tile, K=64.
__global__ __launch_bounds__(256) void k4_mfma(const u16* __restrict__ hb,
        const void* __restrict__ W2, const void* __restrict__ b2,
        const int* __restrict__ flag, u16* __restrict__ params) {
    __shared__ u16 As[64 * SA];   // hidden [m][k]
    __shared__ u16 Bs[64 * SA];   // W2^T   [n][k]
    const int tid = threadIdx.x;
    const int m0 = blockIdx.x * 64, n0 = blockIdx.y * 64;
    const int isbf = *flag;
    const int lane = tid & 63, w = tid >> 6;
    const int wm = w & 1, wn = w >> 1;
    const int l16 = lane & 15, quad = lane >> 4;
    // stage A: 16 contiguous bf16 per thread
    {
        const int row = tid >> 2, kp = (tid & 3) * 16;
        const u16x8* ga = (const u16x8*)&hb[(size_t)(m0 + row) * 64 + kp];
        *(u16x8*)&As[row * SA + kp]     = ga[0];
        *(u16x8*)&As[row * SA + kp + 8] = ga[1];
    }
    // stage B^T: thread owns col n, 16 k values (coalesced across lanes)
    {
        const int n = tid & 63, kp = (tid >> 6) * 16;
        u16x8 b0, b1;
#pragma unroll
        for (int j = 0; j < 8; j++) {
            b0[j] = f2bf(loadf(W2, (size_t)(kp + j) * 8192 + n0 + n, isbf));
            b1[j] = f2bf(loadf(W2, (size_t)(kp + 8 + j) * 8192 + n0 + n, isbf));
        }
        *(u16x8*)&Bs[n * SA + kp]     = b0;
        *(u16x8*)&Bs[n * SA + kp + 8] = b1;
    }
    __syncthreads();
    f32x4 acc[2][2];
#pragma unroll
    for (int i = 0; i < 2; i++)
#pragma unroll
        for (int j = 0; j < 2; j++) acc[i][j] = (f32x4){0.f, 0.f, 0.f, 0.f};
#pragma unroll
    for (int kk = 0; kk < 64; kk += 32) {
        bf16x8 af[2], bf[2];
        af[0] = *(const bf16x8*)&As[(wm * 32 + l16) * SA + kk + quad * 8];
        af[1] = *(const bf16x8*)&As[(wm * 32 + 16 + l16) * SA + kk + quad * 8];
        bf[0] = *(const bf16x8*)&Bs[(wn * 32 + l16) * SA + kk + quad * 8];
        bf[1] = *(const bf16x8*)&Bs[(wn * 32 + 16 + l16) * SA + kk + quad * 8];
#pragma unroll
        for (int tm = 0; tm < 2; tm++)
#pragma unroll
            for (int tn = 0; tn < 2; tn++)
                acc[tm][tn] = MFMA(af[tm], bf[tn], acc[tm][tn]);
    }
    float bb[2];
    bb[0] = loadf(b2, n0 + wn * 32 + l16, isbf);
    bb[1] = loadf(b2, n0 + wn * 32 + 16 + l16, isbf);
#pragma unroll
    for (int tm = 0; tm < 2; tm++)
#pragma unroll
        for (int tn = 0; tn < 2; tn++)
#pragma unroll
            for (int r = 0; r < 4; r++) {
                int row = m0 + wm * 32 + tm * 16 + quad * 4 + r;
                int col = n0 + wn * 32 + tn * 16 + l16;
                params[(size_t)row * 8192 + col] = f2bf(acc[tm][tn][r] + bb[tn]);
            }
}

// ---------------- k5: MFMA adaptive mixing, one token per block ------------
__global__ __launch_bounds__(256) void k5_mfma(const u16* __restrict__ params,
        const void* __restrict__ m_beta, const void* __restrict__ s_beta,
        const int* __restrict__ flag, u16* __restrict__ sampled) {
    __shared__ u16 S[64 * SA];    // sampled [p][c]
    __shared__ u16 CMT[64 * SA];  // cm^T [d][c]
    __shared__ u16 SM[64 * SA];   // sm [o][p]
    __shared__ u16 X1T[64 * SA];  // x1^T [d][p]
    const int t = blockIdx.x, tid = threadIdx.x;
    const int isbf = *flag;
    const size_t pbase = (size_t)t * 8192, sbase = (size_t)t * 4096;
    const int lane = tid & 63, w = tid >> 6;
    const int wm = w & 1, wn = w >> 1;
    const int l16 = lane & 15, quad = lane >> 4;
    // stage S (rows p, contiguous c) and SM (rows o, contiguous p)
    {
        const int r = tid >> 2, cp = (tid & 3) * 16;
        const u16x8* gs = (const u16x8*)&sampled[sbase + r * 64 + cp];
        *(u16x8*)&S[r * SA + cp]     = gs[0];
        *(u16x8*)&S[r * SA + cp + 8] = gs[1];
        const u16x8* gm = (const u16x8*)&params[pbase + 4096 + r * 64 + cp];
        *(u16x8*)&SM[r * SA + cp]     = gm[0];
        *(u16x8*)&SM[r * SA + cp + 8] = gm[1];
    }
    // stage CM^T: thread owns col d, 16 c values (coalesced across lanes)
    {
        const int d = tid & 63, cp = (tid >> 6) * 16;
        u16x8 b0, b1;
#pragma unroll
        for (int j = 0; j < 8; j++) {
            b0[j] = params[pbase + (size_t)(cp + j) * 64 + d];
            b1[j] = params[pbase + (size_t)(cp + 8 + j) * 64 + d];
        }
        *(u16x8*)&CMT[d * SA + cp]     = b0;
        *(u16x8*)&CMT[d * SA + cp + 8] = b1;
    }
    __syncthreads();
    // GEMM1: x1[p][d] = gelu(S @ cm + m_beta)
    f32x4 acc[2][2];
#pragma unroll
    for (int i = 0; i < 2; i++)
#pragma unroll
        for (int j = 0; j < 2; j++) acc[i][j] = (f32x4){0.f, 0.f, 0.f, 0.f};
#pragma unroll
    for (int kk = 0; kk < 64; kk += 32) {
        bf16x8 af[2], bf[2];
        af[0] = *(const bf16x8*)&S[(wm * 32 + l16) * SA + kk + quad * 8];
        af[1] = *(const bf16x8*)&S[(wm * 32 + 16 + l16) * SA + kk + quad * 8];
        bf[0] = *(const bf16x8*)&CMT[(wn * 32 + l16) * SA + kk + quad * 8];
        bf[1] = *(const bf16x8*)&CMT[(wn * 32 + 16 + l16) * SA + kk + quad * 8];
#pragma unroll
        for (int tm = 0; tm < 2; tm++)
#pragma unroll
            for (int tn = 0; tn < 2; tn++)
                acc[tm][tn] = MFMA(af[tm], bf[tn], acc[tm][tn]);
    }
    float mb[2];
    mb[0] = loadf(m_beta, wn * 32 + l16, isbf);
    mb[1] = loadf(m_beta, wn * 32 + 16 + l16, isbf);
#pragma unroll
    for (int tm = 0; tm < 2; tm++)
#pragma unroll
        for (int tn = 0; tn < 2; tn++)
#pragma unroll
            for (int r = 0; r < 4; r++) {
                int p = wm * 32 + tm * 16 + quad * 4 + r;
                int d = wn * 32 + tn * 16 + l16;
                X1T[d * SA + p] = f2bf(gelu(acc[tm][tn][r] + mb[tn]));
            }
    __syncthreads();
    // GEMM2: x2[o][d] = gelu(SM @ x1 + s_beta[o])
#pragma unroll
    for (int i = 0; i < 2; i++)
#pragma unroll
        for (int j = 0; j < 2; j++) acc[i][j] = (f32x4){0.f, 0.f, 0.f, 0.f};
#pragma unroll
    for (int kk = 0; kk < 64; kk += 32) {
        bf16x8 af[2], bf[2];
        af[0] = *(const bf16x8*)&SM[(wm * 32 + l16) * SA + kk + quad * 8];
        af[1] = *(const bf16x8*)&SM[(wm * 32 + 16 + l16) * SA + kk + quad * 8];
        bf[0] = *(const bf16x8*)&X1T[(wn * 32 + l16) * SA + kk + quad * 8];
        bf[1] = *(const bf16x8*)&X1T[(wn * 32 + 16 + l16) * SA + kk + quad * 8];
#pragma unroll
        for (int tm = 0; tm < 2; tm++)
#pragma unroll
            for (int tn = 0; tn < 2; tn++)
                acc[tm][tn] = MFMA(af[tm], bf[tn], acc[tm][tn]);
    }
#pragma unroll
    for (int tm = 0; tm < 2; tm++)
#pragma unroll
        for (int tn = 0; tn < 2; tn++)
#pragma unroll
            for (int r = 0; r < 4; r++) {
                int o = wm * 32 + tm * 16 + quad * 4 + r;
                int d = wn * 32 + tn * 16 + l16;
                float sb = loadf(s_beta, o, isbf);
                sampled[sbase + o * 64 + d] = f2bf(gelu(acc[tm][tn][r] + sb));
            }
}

// ---------------- k6: MFMA out = x2 @ W_out + b_out -> fp32 ----------------
// grid (64 m, 4 n), block 256 = 4 waves; 64x64 tile, K-loop 4096 by 64.
__global__ __launch_bounds__(256) void k6_mfma(const u16* __restrict__ x2b,
        const void* __restrict__ W_out, const void* __restrict__ b_out,
        const int* __restrict__ flag, float* __restrict__ out) {
    __shared__ u16 As[64 * SA];   // x2 [m][k] tile
    __shared__ u16 Bs[64 * SA];   // W_out^T [n][k] tile
    const int tid = threadIdx.x;
    const int m0 = blockIdx.x * 64, n0 = blockIdx.y * 64;
    const int isbf = *flag;
    const int lane = tid & 63, w = tid >> 6;
    const int wm = w & 1, wn = w >> 1;
    const int l16 = lane & 15, quad = lane >> 4;
    const int sArow = tid >> 2, sAk = (tid & 3) * 16;
    const int sBn = tid & 63, sBk = (tid >> 6) * 16;
    f32x4 acc[2][2];
#pragma unroll
    for (int i = 0; i < 2; i++)
#pragma unroll
        for (int j = 0; j < 2; j++) acc[i][j] = (f32x4){0.f, 0.f, 0.f, 0.f};
    for (int k0 = 0; k0 < 4096; k0 += 64) {
        // global loads first (overlap with previous compute before barrier)
        const u16x8* ga = (const u16x8*)&x2b[(size_t)(m0 + sArow) * 4096 + k0 + sAk];
        u16x8 a0 = ga[0], a1 = ga[1];
        u16x8 b0, b1;
#pragma unroll
        for (int j = 0; j < 8; j++) {
            b0[j] = f2bf(loadf(W_out, (size_t)(k0 + sBk + j) * 256 + n0 + sBn, isbf));
            b1[j] = f2bf(loadf(W_out, (size_t)(k0 + sBk + 8 + j) * 256 + n0 + sBn, isbf));
        }
        __syncthreads();   // previous iteration's fragment reads complete
        *(u16x8*)&As[sArow * SA + sAk]     = a0;
        *(u16x8*)&As[sArow * SA + sAk + 8] = a1;
        *(u16x8*)&Bs[sBn * SA + sBk]       = b0;
        *(u16x8*)&Bs[sBn * SA + sBk + 8]   = b1;
        __syncthreads();
#pragma unroll
        for (int kk = 0; kk < 64; kk += 32) {
            bf16x8 af[2], bf[2];
            af[0] = *(const bf16x8*)&As[(wm * 32 + l16) * SA + kk + quad * 8];
            af[1] = *(const bf16x8*)&As[(wm * 32 + 16 + l16) * SA + kk + quad * 8];
            bf[0] = *(const bf16x8*)&Bs[(wn * 32 + l16) * SA + kk + quad * 8];
            bf[1] = *(const bf16x8*)&Bs[(wn * 32 + 16 + l16) * SA + kk + quad * 8];
#pragma unroll
            for (int tm = 0; tm < 2; tm++)
#pragma unroll
                for (int tn = 0; tn < 2; tn++)
                    acc[tm][tn] = MFMA(af[tm], bf[tn], acc[tm][tn]);
        }
    }
    float bo[2];
    bo[0] = loadf(b_out, n0 + wn * 32 + l16, isbf);
    bo[1] = loadf(b_out, n0 + wn * 32 + 16 + l16, isbf);
#pragma unroll
    for (int tm = 0; tm < 2; tm++)
#pragma unroll
        for (int tn = 0; tn < 2; tn++)
#pragma unroll
            for (int r = 0; r < 4; r++) {
                int row = m0 + wm * 32 + tm * 16 + quad * 4 + r;
                int col = n0 + wn * 32 + tn * 16 + l16;
                out[(size_t)row * 256 + col] = acc[tm][tn][r] + bo[tn];
            }
}

extern "C" void kernel_launch(void* const* d_in, const int* in_sizes, int n_in,
                              void* d_out, int out_size, void* d_ws, size_t ws_size,
                              hipStream_t stream) {
    const void* img    = d_in[0];
    const void* roi    = d_in[1];
    const void* query  = d_in[2];
    const void* W_off  = d_in[3];
    const void* b_off  = d_in[4];
    const void* ln_w   = d_in[5];
    const void* ln_b   = d_in[6];
    const void* W1     = d_in[7];
    const void* b1     = d_in[8];
    const void* W2     = d_in[9];
    const void* b2     = d_in[10];
    const void* m_beta = d_in[11];
    const void* s_beta = d_in[12];
    const void* W_out  = d_in[13];
    const void* b_out  = d_in[14];

    char* ws = (char*)d_ws;
    // ws layout (bytes):
    //   flag    @ 0
    //   pts     @ 1,024       : 4096*128*4  = 2,097,152 (fp32)   -> 2,098,176
    //   hidden  @ 2,098,176   : 4096*64*2   = 524,288  (bf16)    -> 2,622,464
    //   sampled @ 2,622,464   : 4096*4096*2 = 33,554,432 (bf16)  -> 36,176,896
    //   params  @ 36,176,896  : 4096*8192*2 = 67,108,864 (bf16)  -> 103,285,760
    //   featT   @ 103,285,760 : 64*3136*256*2 = 102,760,448 (tier A) -> 206,046,208
    int*   flag    = (int*)(ws + 0);
    float* pts     = (float*)(ws + 1024);
    u16*   hbuf    = (u16*)(ws + 2098176);
    u16*   sampled = (u16*)(ws + 2622464);
    u16*   params  = (u16*)(ws + 36176896);
    u16*   featT   = (u16*)(ws + 103285760);
    const bool tierA = ws_size >= (size_t)206046208;

    kdetect<<<1, 64, 0, stream>>>(ln_w, flag);
    k1_points<<<4096, 256, 0, stream>>>(query, roi, W_off, b_off, ln_w, ln_b, W1, b1,
                                        flag, pts, hbuf);
    if (tierA) {
        k0_transpose<<<dim3(49, 4, 64), 256, 0, stream>>>(img, featT, flag);
        k2_sample_t<<<4096, 256, 0, stream>>>(featT, pts, sampled);
    } else {
        k2_sample_d<<<4096, 256, 0, stream>>>(img, pts, sampled, flag);
    }
    k4_mfma<<<dim3(64, 128), 256, 0, stream>>>(hbuf, W2, b2, flag, params);
    k5_mfma<<<4096, 256, 0, stream>>>(params, m_beta, s_beta, flag, sampled);
    k6_mfma<<<dim3(64, 4), 256, 0, stream>>>(sampled, W_out, b_out, flag, (float*)d_out);
}

// Round 5
// 551.172 us; speedup vs baseline: 2.4535x; 1.0685x over previous
//
#include <hip/hip_runtime.h>

// SparseFormer forward, MI355X gfx950. Round 5:
//  - prep: transpose-convert W2 -> W2T[8192][64] bf16, W_out -> W_outT[256][4096] bf16
//          => k4/k6 B-staging becomes pure b128 vector loads (no scalar fp32 + f2bf in loop)
//  - k6: split-K x2 (grid 64x4x2, 2 blocks/CU) -> fp32 partials + k7_reduce(+bias)
// Pipeline: kdetect, k1(points+hidden), k0(transpose img), k2(gather),
//           ktrans(W2), ktrans(W_out), k4(params GEMM), k5(mixing), k6(out GEMM), k7(reduce)
// MFMA 16x16x32 bf16 layouts (HW-verified): A: m=lane&15,k=quad*8+j ;
// B: n=lane&15,k=quad*8+j (LDS holds B^T rows) ; C/D: col=lane&15, row=quad*4+reg.
// LDS tiles stride SA=72 bf16 -> conflict-balanced ds_read_b128 fragments.

typedef unsigned short u16;
typedef u16 u16x8 __attribute__((ext_vector_type(8)));
typedef short bf16x8 __attribute__((ext_vector_type(8)));
typedef float f32x4 __attribute__((ext_vector_type(4)));
#define SA 72
#define MFMA(a, b, c) __builtin_amdgcn_mfma_f32_16x16x32_bf16(a, b, c, 0, 0, 0)

static __device__ __forceinline__ float bf2f(u16 s) {
    union { float f; unsigned u; } v; v.u = ((unsigned)s) << 16; return v.f;
}
static __device__ __forceinline__ u16 f2bf(float f) {
    union { float f; unsigned u; } v; v.f = f;
    unsigned r = v.u + 0x7fffu + ((v.u >> 16) & 1u);   // RNE
    return (u16)(r >> 16);
}
static __device__ __forceinline__ float gelu(float x) {
    return 0.5f * x * (1.0f + erff(x * 0.70710678118654752f));
}
static __device__ __forceinline__ float loadf(const void* p, size_t i, int isbf) {
    return isbf ? bf2f(((const u16*)p)[i]) : ((const float*)p)[i];
}

// ---------------- dtype detect --------------------------------------------
__global__ void kdetect(const void* __restrict__ lnw, int* __restrict__ flag) {
    if (threadIdx.x == 0) {
        unsigned v = *(const unsigned*)lnw;
        *flag = (v == 0x3F800000u) ? 0 : 1;
    }
}

// ---------------- generic transpose-convert: src[R][C] -> dst[C][R] bf16 ---
__global__ void ktrans_bf(const void* __restrict__ src, u16* __restrict__ dst,
                          int R, int C, const int* __restrict__ flag) {
    __shared__ __align__(16) float tile[64 * 65];
    const int c0 = blockIdx.x * 64, r0 = blockIdx.y * 64;
    const int tid = threadIdx.x;
    const int isbf = *flag;
#pragma unroll
    for (int i = 0; i < 16; i++) {
        int e = i * 256 + tid;
        int rr = e >> 6, cc = e & 63;
        tile[rr * 65 + cc] = loadf(src, (size_t)(r0 + rr) * C + c0 + cc, isbf);
    }
    __syncthreads();
#pragma unroll
    for (int i = 0; i < 16; i++) {
        int e = i * 256 + tid;
        int cc = e >> 6, rr = e & 63;
        dst[(size_t)(c0 + cc) * R + r0 + rr] = f2bf(tile[rr * 65 + cc]);
    }
}

// ---------------- k0: transpose img (B,256,3136) -> (B,3136,256) bf16 ------
__global__ void k0_transpose(const void* __restrict__ img, u16* __restrict__ featT,
                             const int* __restrict__ flag) {
    __shared__ __align__(16) float tile[64 * 65];
    const int pos0 = blockIdx.x * 64, c0 = blockIdx.y * 64, bz = blockIdx.z;
    const int tid = threadIdx.x;
    const int isbf = *flag;
#pragma unroll
    for (int i = 0; i < 16; i++) {
        int e = i * 256 + tid;
        int cy = e >> 6, px = e & 63;
        tile[cy * 65 + px] = loadf(img, ((size_t)bz * 256 + c0 + cy) * 3136 + pos0 + px, isbf);
    }
    __syncthreads();
#pragma unroll
    for (int i = 0; i < 16; i++) {
        int e = i * 256 + tid;
        int cy = e & 63, px = e >> 6;
        featT[((size_t)bz * 3136 + pos0 + px) * 256 + c0 + cy] = f2bf(tile[cy * 65 + px]);
    }
}

// ---------------- k1: offsets -> pts ; LN -> hidden(bf16) ------------------
__global__ void k1_points(const void* __restrict__ query, const void* __restrict__ roi,
                          const void* __restrict__ W_off, const void* __restrict__ b_off,
                          const void* __restrict__ ln_w, const void* __restrict__ ln_b,
                          const void* __restrict__ W1, const void* __restrict__ b1,
                          const int* __restrict__ flag,
                          float* __restrict__ pts, u16* __restrict__ hbuf) {
    __shared__ float qf[256], qn[256], offl[128], red[4], stats[8];
    const int t = blockIdx.x, tid = threadIdx.x;
    const int isbf = *flag;
    float q = loadf(query, (size_t)t * 256 + tid, isbf);
    qf[tid] = q;
    float v = q;
#pragma unroll
    for (int o = 32; o; o >>= 1) v += __shfl_down(v, o, 64);
    if ((tid & 63) == 0) red[tid >> 6] = v;
    __syncthreads();
    if (tid == 0) stats[0] = (red[0] + red[1] + red[2] + red[3]) * (1.f / 256.f);
    __syncthreads();
    float mu = stats[0];
    float dv = q - mu;
    v = dv * dv;
#pragma unroll
    for (int o = 32; o; o >>= 1) v += __shfl_down(v, o, 64);
    if ((tid & 63) == 0) red[tid >> 6] = v;
    __syncthreads();
    if (tid == 0) stats[1] = (red[0] + red[1] + red[2] + red[3]) * (1.f / 256.f);
    __syncthreads();
    float inv = rsqrtf(stats[1] + 1e-6f);
    qn[tid] = dv * inv * loadf(ln_w, tid, isbf) + loadf(ln_b, tid, isbf);
    __syncthreads();
    if (tid < 128) {                        // offsets use RAW query
        float a = loadf(b_off, tid, isbf);
        for (int d = 0; d < 256; d++) a = fmaf(qf[d], loadf(W_off, (size_t)d * 128 + tid, isbf), a);
        offl[tid] = a;
    } else if (tid < 192) {                 // hidden uses LN'd query
        int k = tid - 128;
        float a = loadf(b1, k, isbf);
        for (int d = 0; d < 256; d++) a = fmaf(qn[d], loadf(W1, (size_t)d * 64 + k, isbf), a);
        hbuf[(size_t)t * 64 + k] = f2bf(a);
    }
    __syncthreads();
    if (tid < 2) {
        float m = 0.f;
        for (int p = 0; p < 64; p++) m += offl[p * 2 + tid];
        m *= (1.f / 64.f);
        float s2 = 0.f;
        for (int p = 0; p < 64; p++) { float d = offl[p * 2 + tid] - m; s2 += d * d; }
        float sd = sqrtf(s2 * (1.f / 63.f));
        stats[2 + tid] = m;
        stats[4 + tid] = 1.f / (3.f * (sd + 1e-7f));
    }
    __syncthreads();
    if (tid < 128) {
        int xy = tid & 1;
        float lo = loadf(roi, (size_t)t * 4 + xy, isbf);
        float hi = loadf(roi, (size_t)t * 4 + 2 + xy, isbf);
        float ctr = 0.5f * (lo + hi), wh = hi - lo;
        pts[(size_t)t * 128 + tid] = ctr + (offl[tid] - stats[2 + xy]) * stats[4 + xy] * wh;
    }
}

// ---------------- k2: bilinear gather --------------------------------------
__global__ void k2_sample_t(const u16* __restrict__ featT, const float* __restrict__ pts,
                            u16* __restrict__ sampled) {
    const int t = blockIdx.x, tid = threadIdx.x;
    const int pt = tid >> 2, cg = tid & 3;
    const int b = t >> 6, hh = pt >> 4;
    const float px = pts[(size_t)t * 128 + pt * 2], py = pts[(size_t)t * 128 + pt * 2 + 1];
    const float x = px * 56.f - 0.5f, y = py * 56.f - 0.5f;
    const float x0f = floorf(x), y0f = floorf(y);
    const int ix0 = (int)x0f, iy0 = (int)y0f;
    const float wx1 = x - x0f, wx0 = 1.f - wx1, wy1 = y - y0f, wy0 = 1.f - wy1;
    float acc[16];
#pragma unroll
    for (int i = 0; i < 16; i++) acc[i] = 0.f;
    const int chbase = hh * 64 + cg * 16;
#pragma unroll
    for (int corner = 0; corner < 4; corner++) {
        const int xi = ix0 + (corner & 1), yi = iy0 + (corner >> 1);
        const float wgt = ((corner & 1) ? wx1 : wx0) * ((corner >> 1) ? wy1 : wy0);
        if (xi >= 0 && xi < 56 && yi >= 0 && yi < 56) {
            const u16x8* p8 = (const u16x8*)&featT[((size_t)b * 3136 + yi * 56 + xi) * 256 + chbase];
            u16x8 a = p8[0], c = p8[1];
#pragma unroll
            for (int i = 0; i < 8; i++) {
                acc[i]     = fmaf(wgt, bf2f(a[i]), acc[i]);
                acc[8 + i] = fmaf(wgt, bf2f(c[i]), acc[8 + i]);
            }
        }
    }
    u16x8 o0, o1;
#pragma unroll
    for (int i = 0; i < 8; i++) { o0[i] = f2bf(acc[i]); o1[i] = f2bf(acc[8 + i]); }
    u16x8* q8 = (u16x8*)&sampled[(size_t)t * 4096 + pt * 64 + cg * 16];
    q8[0] = o0; q8[1] = o1;
}

__global__ void k2_sample_d(const void* __restrict__ img, const float* __restrict__ pts,
                            u16* __restrict__ sampled, const int* __restrict__ flag) {
    const int t = blockIdx.x, tid = threadIdx.x;
    const int pt = tid >> 2, cg = tid & 3;
    const int b = t >> 6, hh = pt >> 4;
    const int isbf = *flag;
    const float px = pts[(size_t)t * 128 + pt * 2], py = pts[(size_t)t * 128 + pt * 2 + 1];
    const float x = px * 56.f - 0.5f, y = py * 56.f - 0.5f;
    const float x0f = floorf(x), y0f = floorf(y);
    const int ix0 = (int)x0f, iy0 = (int)y0f;
    const float wx1 = x - x0f, wx0 = 1.f - wx1, wy1 = y - y0f, wy0 = 1.f - wy1;
    float acc[16];
#pragma unroll
    for (int i = 0; i < 16; i++) acc[i] = 0.f;
    const int chbase = b * 256 + hh * 64 + cg * 16;
#pragma unroll
    for (int corner = 0; corner < 4; corner++) {
        const int xi = ix0 + (corner & 1), yi = iy0 + (corner >> 1);
        const float wgt = ((corner & 1) ? wx1 : wx0) * ((corner >> 1) ? wy1 : wy0);
        if (xi >= 0 && xi < 56 && yi >= 0 && yi < 56) {
            const size_t sp = yi * 56 + xi;
#pragma unroll
            for (int i = 0; i < 16; i++)
                acc[i] = fmaf(wgt, loadf(img, ((size_t)(chbase + i)) * 3136 + sp, isbf), acc[i]);
        }
    }
    for (int i = 0; i < 16; i++)
        sampled[(size_t)t * 4096 + pt * 64 + cg * 16 + i] = f2bf(acc[i]);
}

// ---------------- k4: MFMA params = hidden @ W2 + b2 -----------------------
// grid (64 m, 128 n), block 256 = 4 waves; 64x64 tile, K=64. B from W2T bf16.
__global__ __launch_bounds__(256) void k4_mfma(const u16* __restrict__ hb,
        const u16* __restrict__ W2T, const void* __restrict__ b2,
        const int* __restrict__ flag, u16* __restrict__ params) {
    __shared__ u16 As[64 * SA];   // hidden [m][k]
    __shared__ u16 Bs[64 * SA];   // W2^T   [n][k]
    const int tid = threadIdx.x;
    const int m0 = blockIdx.x * 64, n0 = blockIdx.y * 64;
    const int isbf = *flag;
    const int lane = tid & 63, w = tid >> 6;
    const int wm = w & 1, wn = w >> 1;
    const int l16 = lane & 15, quad = lane >> 4;
    {
        const int row = tid >> 2, kp = (tid & 3) * 16;
        const u16x8* ga = (const u16x8*)&hb[(size_t)(m0 + row) * 64 + kp];
        *(u16x8*)&As[row * SA + kp]     = ga[0];
        *(u16x8*)&As[row * SA + kp + 8] = ga[1];
        const u16x8* gb = (const u16x8*)&W2T[(size_t)(n0 + row) * 64 + kp];
        *(u16x8*)&Bs[row * SA + kp]     = gb[0];
        *(u16x8*)&Bs[row * SA + kp + 8] = gb[1];
    }
    __syncthreads();
    f32x4 acc[2][2];
#pragma unroll
    for (int i = 0; i < 2; i++)
#pragma unroll
        for (int j = 0; j < 2; j++) acc[i][j] = (f32x4){0.f, 0.f, 0.f, 0.f};
#pragma unroll
    for (int kk = 0; kk < 64; kk += 32) {
        bf16x8 af[2], bfr[2];
        af[0]  = *(const bf16x8*)&As[(wm * 32 + l16) * SA + kk + quad * 8];
        af[1]  = *(const bf16x8*)&As[(wm * 32 + 16 + l16) * SA + kk + quad * 8];
        bfr[0] = *(const bf16x8*)&Bs[(wn * 32 + l16) * SA + kk + quad * 8];
        bfr[1] = *(const bf16x8*)&Bs[(wn * 32 + 16 + l16) * SA + kk + quad * 8];
#pragma unroll
        for (int tm = 0; tm < 2; tm++)
#pragma unroll
            for (int tn = 0; tn < 2; tn++)
                acc[tm][tn] = MFMA(af[tm], bfr[tn], acc[tm][tn]);
    }
    float bb[2];
    bb[0] = loadf(b2, n0 + wn * 32 + l16, isbf);
    bb[1] = loadf(b2, n0 + wn * 32 + 16 + l16, isbf);
#pragma unroll
    for (int tm = 0; tm < 2; tm++)
#pragma unroll
        for (int tn = 0; tn < 2; tn++)
#pragma unroll
            for (int r = 0; r < 4; r++) {
                int row = m0 + wm * 32 + tm * 16 + quad * 4 + r;
                int col = n0 + wn * 32 + tn * 16 + l16;
                params[(size_t)row * 8192 + col] = f2bf(acc[tm][tn][r] + bb[tn]);
            }
}

// ---------------- k5: MFMA adaptive mixing, one token per block ------------
__global__ __launch_bounds__(256) void k5_mfma(const u16* __restrict__ params,
        const void* __restrict__ m_beta, const void* __restrict__ s_beta,
        const int* __restrict__ flag, u16* __restrict__ sampled) {
    __shared__ u16 S[64 * SA];    // sampled [p][c]
    __shared__ u16 CMT[64 * SA];  // cm^T [d][c]
    __shared__ u16 SM[64 * SA];   // sm [o][p]
    __shared__ u16 X1T[64 * SA];  // x1^T [d][p]
    const int t = blockIdx.x, tid = threadIdx.x;
    const int isbf = *flag;
    const size_t pbase = (size_t)t * 8192, sbase = (size_t)t * 4096;
    const int lane = tid & 63, w = tid >> 6;
    const int wm = w & 1, wn = w >> 1;
    const int l16 = lane & 15, quad = lane >> 4;
    {
        const int r = tid >> 2, cp = (tid & 3) * 16;
        const u16x8* gs = (const u16x8*)&sampled[sbase + r * 64 + cp];
        *(u16x8*)&S[r * SA + cp]     = gs[0];
        *(u16x8*)&S[r * SA + cp + 8] = gs[1];
        const u16x8* gm = (const u16x8*)&params[pbase + 4096 + r * 64 + cp];
        *(u16x8*)&SM[r * SA + cp]     = gm[0];
        *(u16x8*)&SM[r * SA + cp + 8] = gm[1];
    }
    {
        const int d = tid & 63, cp = (tid >> 6) * 16;
        u16x8 b0, b1;
#pragma unroll
        for (int j = 0; j < 8; j++) {
            b0[j] = params[pbase + (size_t)(cp + j) * 64 + d];
            b1[j] = params[pbase + (size_t)(cp + 8 + j) * 64 + d];
        }
        *(u16x8*)&CMT[d * SA + cp]     = b0;
        *(u16x8*)&CMT[d * SA + cp + 8] = b1;
    }
    __syncthreads();
    // GEMM1: x1[p][d] = gelu(S @ cm + m_beta)
    f32x4 acc[2][2];
#pragma unroll
    for (int i = 0; i < 2; i++)
#pragma unroll
        for (int j = 0; j < 2; j++) acc[i][j] = (f32x4){0.f, 0.f, 0.f, 0.f};
#pragma unroll
    for (int kk = 0; kk < 64; kk += 32) {
        bf16x8 af[2], bfr[2];
        af[0]  = *(const bf16x8*)&S[(wm * 32 + l16) * SA + kk + quad * 8];
        af[1]  = *(const bf16x8*)&S[(wm * 32 + 16 + l16) * SA + kk + quad * 8];
        bfr[0] = *(const bf16x8*)&CMT[(wn * 32 + l16) * SA + kk + quad * 8];
        bfr[1] = *(const bf16x8*)&CMT[(wn * 32 + 16 + l16) * SA + kk + quad * 8];
#pragma unroll
        for (int tm = 0; tm < 2; tm++)
#pragma unroll
            for (int tn = 0; tn < 2; tn++)
                acc[tm][tn] = MFMA(af[tm], bfr[tn], acc[tm][tn]);
    }
    float mb[2];
    mb[0] = loadf(m_beta, wn * 32 + l16, isbf);
    mb[1] = loadf(m_beta, wn * 32 + 16 + l16, isbf);
#pragma unroll
    for (int tm = 0; tm < 2; tm++)
#pragma unroll
        for (int tn = 0; tn < 2; tn++)
#pragma unroll
            for (int r = 0; r < 4; r++) {
                int p = wm * 32 + tm * 16 + quad * 4 + r;
                int d = wn * 32 + tn * 16 + l16;
                X1T[d * SA + p] = f2bf(gelu(acc[tm][tn][r] + mb[tn]));
            }
    __syncthreads();
    // GEMM2: x2[o][d] = gelu(SM @ x1 + s_beta[o])
#pragma unroll
    for (int i = 0; i < 2; i++)
#pragma unroll
        for (int j = 0; j < 2; j++) acc[i][j] = (f32x4){0.f, 0.f, 0.f, 0.f};
#pragma unroll
    for (int kk = 0; kk < 64; kk += 32) {
        bf16x8 af[2], bfr[2];
        af[0]  = *(const bf16x8*)&SM[(wm * 32 + l16) * SA + kk + quad * 8];
        af[1]  = *(const bf16x8*)&SM[(wm * 32 + 16 + l16) * SA + kk + quad * 8];
        bfr[0] = *(const bf16x8*)&X1T[(wn * 32 + l16) * SA + kk + quad * 8];
        bfr[1] = *(const bf16x8*)&X1T[(wn * 32 + 16 + l16) * SA + kk + quad * 8];
#pragma unroll
        for (int tm = 0; tm < 2; tm++)
#pragma unroll
            for (int tn = 0; tn < 2; tn++)
                acc[tm][tn] = MFMA(af[tm], bfr[tn], acc[tm][tn]);
    }
#pragma unroll
    for (int tm = 0; tm < 2; tm++)
#pragma unroll
        for (int tn = 0; tn < 2; tn++)
#pragma unroll
            for (int r = 0; r < 4; r++) {
                int o = wm * 32 + tm * 16 + quad * 4 + r;
                int d = wn * 32 + tn * 16 + l16;
                float sb = loadf(s_beta, o, isbf);
                sampled[sbase + o * 64 + d] = f2bf(gelu(acc[tm][tn][r] + sb));
            }
}

// ---------------- k6: MFMA partial = x2 @ W_out (split-K x2) ---------------
// grid (64 m, 4 n, 2 kz), block 256 = 4 waves; 64x64 tile, K-half 2048 by 64.
__global__ __launch_bounds__(256) void k6_mfma(const u16* __restrict__ x2b,
        const u16* __restrict__ WoutT, float* __restrict__ part) {
    __shared__ u16 As[64 * SA];   // x2 [m][k] tile
    __shared__ u16 Bs[64 * SA];   // W_out^T [n][k] tile
    const int tid = threadIdx.x;
    const int m0 = blockIdx.x * 64, n0 = blockIdx.y * 64, kz = blockIdx.z;
    const int lane = tid & 63, w = tid >> 6;
    const int wm = w & 1, wn = w >> 1;
    const int l16 = lane & 15, quad = lane >> 4;
    const int sRow = tid >> 2, sK = (tid & 3) * 16;
    f32x4 acc[2][2];
#pragma unroll
    for (int i = 0; i < 2; i++)
#pragma unroll
        for (int j = 0; j < 2; j++) acc[i][j] = (f32x4){0.f, 0.f, 0.f, 0.f};
    const int kbeg = kz * 2048, kend = kbeg + 2048;
    for (int k0 = kbeg; k0 < kend; k0 += 64) {
        const u16x8* ga = (const u16x8*)&x2b[(size_t)(m0 + sRow) * 4096 + k0 + sK];
        u16x8 a0 = ga[0], a1 = ga[1];
        const u16x8* gb = (const u16x8*)&WoutT[(size_t)(n0 + sRow) * 4096 + k0 + sK];
        u16x8 b0 = gb[0], b1 = gb[1];
        __syncthreads();   // previous iteration's fragment reads complete
        *(u16x8*)&As[sRow * SA + sK]     = a0;
        *(u16x8*)&As[sRow * SA + sK + 8] = a1;
        *(u16x8*)&Bs[sRow * SA + sK]     = b0;
        *(u16x8*)&Bs[sRow * SA + sK + 8] = b1;
        __syncthreads();
#pragma unroll
        for (int kk = 0; kk < 64; kk += 32) {
            bf16x8 af[2], bfr[2];
            af[0]  = *(const bf16x8*)&As[(wm * 32 + l16) * SA + kk + quad * 8];
            af[1]  = *(const bf16x8*)&As[(wm * 32 + 16 + l16) * SA + kk + quad * 8];
            bfr[0] = *(const bf16x8*)&Bs[(wn * 32 + l16) * SA + kk + quad * 8];
            bfr[1] = *(const bf16x8*)&Bs[(wn * 32 + 16 + l16) * SA + kk + quad * 8];
#pragma unroll
            for (int tm = 0; tm < 2; tm++)
#pragma unroll
                for (int tn = 0; tn < 2; tn++)
                    acc[tm][tn] = MFMA(af[tm], bfr[tn], acc[tm][tn]);
        }
    }
    float* pbase = part + (size_t)kz * (4096 * 256);
#pragma unroll
    for (int tm = 0; tm < 2; tm++)
#pragma unroll
        for (int tn = 0; tn < 2; tn++)
#pragma unroll
            for (int r = 0; r < 4; r++) {
                int row = m0 + wm * 32 + tm * 16 + quad * 4 + r;
                int col = n0 + wn * 32 + tn * 16 + l16;
                pbase[(size_t)row * 256 + col] = acc[tm][tn][r];
            }
}

// ---------------- k7: out = part0 + part1 + b_out --------------------------
__global__ void k7_reduce(const float* __restrict__ part, const void* __restrict__ b_out,
                          const int* __restrict__ flag, float* __restrict__ out) {
    const int i = blockIdx.x * 256 + threadIdx.x;
    const int isbf = *flag;
    out[i] = part[i] + part[4096 * 256 + i] + loadf(b_out, i & 255, isbf);
}

extern "C" void kernel_launch(void* const* d_in, const int* in_sizes, int n_in,
                              void* d_out, int out_size, void* d_ws, size_t ws_size,
                              hipStream_t stream) {
    const void* img    = d_in[0];
    const void* roi    = d_in[1];
    const void* query  = d_in[2];
    const void* W_off  = d_in[3];
    const void* b_off  = d_in[4];
    const void* ln_w   = d_in[5];
    const void* ln_b   = d_in[6];
    const void* W1     = d_in[7];
    const void* b1     = d_in[8];
    const void* W2     = d_in[9];
    const void* b2     = d_in[10];
    const void* m_beta = d_in[11];
    const void* s_beta = d_in[12];
    const void* W_out  = d_in[13];
    const void* b_out  = d_in[14];

    char* ws = (char*)d_ws;
    // ws layout (bytes):
    //   flag    @ 0
    //   pts     @ 1,024        : 2,097,152  (fp32)   -> 2,098,176
    //   hidden  @ 2,098,176    : 524,288    (bf16)   -> 2,622,464
    //   sampled @ 2,622,464    : 33,554,432 (bf16)   -> 36,176,896
    //   params  @ 36,176,896   : 67,108,864 (bf16)   -> 103,285,760
    //   W2T     @ 103,285,760  : 1,048,576  (bf16)   -> 104,334,336
    //   WoutT   @ 104,334,336  : 2,097,152  (bf16)   -> 106,431,488
    //   part    @ 106,431,488  : 8,388,608  (fp32)   -> 114,820,096
    //   featT   @ 114,820,096  : 102,760,448 (bf16, tier A) -> 217,580,544
    int*   flag    = (int*)(ws + 0);
    float* pts     = (float*)(ws + 1024);
    u16*   hbuf    = (u16*)(ws + 2098176);
    u16*   sampled = (u16*)(ws + 2622464);
    u16*   params  = (u16*)(ws + 36176896);
    u16*   W2T     = (u16*)(ws + 103285760);
    u16*   WoutT   = (u16*)(ws + 104334336);
    float* part    = (float*)(ws + 106431488);
    u16*   featT   = (u16*)(ws + 114820096);
    const bool tierA = ws_size >= (size_t)217580544;

    kdetect<<<1, 64, 0, stream>>>(ln_w, flag);
    k1_points<<<4096, 256, 0, stream>>>(query, roi, W_off, b_off, ln_w, ln_b, W1, b1,
                                        flag, pts, hbuf);
    ktrans_bf<<<dim3(128, 1), 256, 0, stream>>>(W2, W2T, 64, 8192, flag);
    ktrans_bf<<<dim3(4, 64), 256, 0, stream>>>(W_out, WoutT, 4096, 256, flag);
    if (tierA) {
        k0_transpose<<<dim3(49, 4, 64), 256, 0, stream>>>(img, featT, flag);
        k2_sample_t<<<4096, 256, 0, stream>>>(featT, pts, sampled);
    } else {
        k2_sample_d<<<4096, 256, 0, stream>>>(img, pts, sampled, flag);
    }
    k4_mfma<<<dim3(64, 128), 256, 0, stream>>>(hbuf, W2T, b2, flag, params);
    k5_mfma<<<4096, 256, 0, stream>>>(params, m_beta, s_beta, flag, sampled);
    k6_mfma<<<dim3(64, 4, 2), 256, 0, stream>>>(sampled, WoutT, part);
    k7_reduce<<<4096, 256, 0, stream>>>(part, b_out, flag, (float*)d_out);
}